// Round 5
// baseline (947.100 us; speedup 1.0000x reference)
//
#include <hip/hip_runtime.h>
#include <math.h>

#define HID 128
#define NHEAD 8
#define NL 3
#define NS 256
#define ROWS 4096
#define NBLK 256
#define BT 512

// ---------------- device-scope grid barrier (256 co-resident blocks) ----------------
__device__ __forceinline__ void gsync(int* cnt, int* gen) {
    __syncthreads();
    if (threadIdx.x == 0) {
        __threadfence();   // release: flush this CU's writes device-wide
        int g = __hip_atomic_load(gen, __ATOMIC_SEQ_CST, __HIP_MEMORY_SCOPE_AGENT);
        int a = __hip_atomic_fetch_add(cnt, 1, __ATOMIC_SEQ_CST, __HIP_MEMORY_SCOPE_AGENT);
        if (a == NBLK - 1) {
            __hip_atomic_store(cnt, 0, __ATOMIC_SEQ_CST, __HIP_MEMORY_SCOPE_AGENT);
            __hip_atomic_fetch_add(gen, 1, __ATOMIC_SEQ_CST, __HIP_MEMORY_SCOPE_AGENT);
        } else {
            while (__hip_atomic_load(gen, __ATOMIC_SEQ_CST, __HIP_MEMORY_SCOPE_AGENT) == g)
                __builtin_amdgcn_s_sleep(1);
        }
        __threadfence();   // acquire: invalidate stale cached lines before reads
    }
    __syncthreads();
}

__global__ void k_init(int* bar) { if (threadIdx.x < 16) bar[threadIdx.x] = 0; }

// ---------------- fused LN + single-shot K=128 GEMM tile (per 256-thread unit) ----
// Ast[128][72] (transposed LN'd A), Ws[128][68]. One block-wide barrier inside.
__device__ __forceinline__ void lngemm_tile(
    const float* __restrict__ x, const float* __restrict__ x2,
    const float* __restrict__ g, const float* __restrict__ b,
    const float* __restrict__ W, float* __restrict__ C,
    int Nc, int row0, int col0, int relu, int act,
    float* __restrict__ Ast, float* __restrict__ Ws, int ht)
{
    if (act) {
        int wk0 = ht >> 3, wn = (ht & 7) * 8;
#pragma unroll
        for (int rep = 0; rep < 4; ++rep) {
            int wk = wk0 + rep * 32;
            const float* wp = W + (long)wk * Nc + col0 + wn;
            *(float4*)&Ws[wk * 68 + wn]     = *(const float4*)wp;
            *(float4*)&Ws[wk * 68 + wn + 4] = *(const float4*)(wp + 4);
        }
#pragma unroll
        for (int pass = 0; pass < 2; ++pass) {
            int row = pass * 32 + (ht >> 3);   // tile-local row
            int p = ht & 7, cb = p * 16;
            float v[16];
            const float* xp = x + (long)(row0 + row) * HID + cb;
#pragma unroll
            for (int j = 0; j < 16; j += 4) *(float4*)&v[j] = *(const float4*)(xp + j);
            if (x2) {
                const float* yp = x2 + (long)(row0 + row) * HID + cb;
#pragma unroll
                for (int j = 0; j < 16; j += 4) {
                    float4 r4 = *(const float4*)(yp + j);
                    v[j] += r4.x; v[j+1] += r4.y; v[j+2] += r4.z; v[j+3] += r4.w;
                }
            }
            float s = 0.f, s2 = 0.f;
#pragma unroll
            for (int j = 0; j < 16; ++j) { s += v[j]; s2 += v[j] * v[j]; }
            s  += __shfl_xor(s, 1);  s  += __shfl_xor(s, 2);  s  += __shfl_xor(s, 4);
            s2 += __shfl_xor(s2, 1); s2 += __shfl_xor(s2, 2); s2 += __shfl_xor(s2, 4);
            float mu  = s * (1.f / HID);
            float var = s2 * (1.f / HID) - mu * mu;
            float inv = rsqrtf(var + 1e-5f);
#pragma unroll
            for (int jj = 0; jj < 16; ++jj) {
                int j = (jj + p) & 15;         // rotate to spread banks
                int c = cb + j;
                Ast[c * 72 + row] = (v[j] - mu) * inv * g[c] + b[c];
            }
        }
    }
    __syncthreads();
    if (act) {
        int tx = ht & 15, ty = ht >> 4;
        float acc[4][4] = {};
#pragma unroll 8
        for (int k = 0; k < HID; ++k) {
            float4 a4 = *(const float4*)&Ast[k * 72 + ty * 4];
            float4 w4 = *(const float4*)&Ws[k * 68 + tx * 4];
            acc[0][0] += a4.x * w4.x; acc[0][1] += a4.x * w4.y; acc[0][2] += a4.x * w4.z; acc[0][3] += a4.x * w4.w;
            acc[1][0] += a4.y * w4.x; acc[1][1] += a4.y * w4.y; acc[1][2] += a4.y * w4.z; acc[1][3] += a4.y * w4.w;
            acc[2][0] += a4.z * w4.x; acc[2][1] += a4.z * w4.y; acc[2][2] += a4.z * w4.z; acc[2][3] += a4.z * w4.w;
            acc[3][0] += a4.w * w4.x; acc[3][1] += a4.w * w4.y; acc[3][2] += a4.w * w4.z; acc[3][3] += a4.w * w4.w;
        }
#pragma unroll
        for (int i = 0; i < 4; ++i) {
            int row = row0 + ty * 4 + i, col = col0 + tx * 4;
            float4 v = make_float4(acc[i][0], acc[i][1], acc[i][2], acc[i][3]);
            if (relu) { v.x = fmaxf(v.x,0.f); v.y = fmaxf(v.y,0.f); v.z = fmaxf(v.z,0.f); v.w = fmaxf(v.w,0.f); }
            *(float4*)(C + (long)row * Nc + col) = v;
        }
    }
}

// ---------------- the persistent mega-kernel ----------------
__global__ __launch_bounds__(BT, 2) void k_mega(
    const float* __restrict__ nf,   const float* __restrict__ ef,
    const float* __restrict__ Wn,   const float* __restrict__ We_in,
    const float* __restrict__ We,
    const float* __restrict__ ln1g, const float* __restrict__ ln1b,
    const float* __restrict__ Wh,
    const float* __restrict__ ln2g, const float* __restrict__ ln2b,
    const float* __restrict__ W1,   const float* __restrict__ W2,
    const float* __restrict__ Wdec,
    float* __restrict__ h, float* __restrict__ y, float* __restrict__ big,
    float* __restrict__ sbuf, int* __restrict__ bar,
    float* __restrict__ out)
{
    extern __shared__ char sm[];
    int t = threadIdx.x;
    int u = t >> 8, ht = t & 255;            // unit (0/1), thread-in-unit
    int nu = blockIdx.x * 2 + u;             // global unit id [0,512)
    int* cnt = bar; int* gen = bar + 1;

    // ---- P0: embed h = nf @ Wn (one float4 per thread), + edge scalars
    {
        int gid = blockIdx.x * BT + t;       // [0, 131072)
        int r = gid >> 5, c4 = (gid & 31) << 2;
        float n0 = nf[2 * r], n1 = nf[2 * r + 1];
        float4 v;
        v.x = n0 * Wn[c4 + 0] + n1 * Wn[HID + c4 + 0];
        v.y = n0 * Wn[c4 + 1] + n1 * Wn[HID + c4 + 1];
        v.z = n0 * Wn[c4 + 2] + n1 * Wn[HID + c4 + 2];
        v.w = n0 * Wn[c4 + 3] + n1 * Wn[HID + c4 + 3];
        *(float4*)&h[(long)r * HID + c4] = v;
        if (blockIdx.x == 0 && t < NL * 2 * NHEAD) {
            int l = t / (2 * NHEAD), j = t % (2 * NHEAD);
            float acc = 0.f;
            for (int c = 0; c < HID; ++c)
                acc += We_in[c] * We[(long)(l * HID + c) * (2 * NHEAD) + j];
            sbuf[t] = acc;
        }
    }
    gsync(cnt, gen);

    for (int l = 0; l < NL; ++l) {
        // ---- P1: LN1 + QKV GEMM. 384 tiles (64 row-tiles x 6 col-tiles).
        {
            float* Ast = (float*)(sm + u * 71680);
            float* Ws  = Ast + 128 * 72;
            int act = (nu < 384);
            int ct = nu >> 6, rt = nu & 63;          // valid when act
            lngemm_tile(h, nullptr, ln1g + l * HID, ln1b + l * HID,
                        Wh + (long)l * HID * 384, big, 384,
                        rt * 64, ct * 64, 0, act, Ast, Ws, ht);
        }
        gsync(cnt, gen);

        // ---- P2: attention. 512 units = b(16) x head(8) x quarter(4).
        {
            float* Ks  = (float*)(sm + u * 53536);   // [256][20]
            float* Vt  = Ks + 256 * 20;              // [16][260]
            float* Pb  = Vt + 16 * 260;              // [4][4][256]
            float* sred= Pb + 4096;                  // [2][2]
            int q4 = nu & 3, hh = (nu >> 2) & 7, bb = nu >> 5;
            int w = ht >> 6, lane = ht & 63;
            {   // K/V staging: one row per thread
                const float* kr = big + ((long)(bb * NS + ht)) * 384 + HID + hh * 16;
                *(float4*)&Ks[ht * 20 + 0]  = *(const float4*)kr;
                *(float4*)&Ks[ht * 20 + 4]  = *(const float4*)(kr + 4);
                *(float4*)&Ks[ht * 20 + 8]  = *(const float4*)(kr + 8);
                *(float4*)&Ks[ht * 20 + 12] = *(const float4*)(kr + 12);
                const float* vr = kr + HID;
                float vv[16];
                *(float4*)&vv[0]  = *(const float4*)vr;
                *(float4*)&vv[4]  = *(const float4*)(vr + 4);
                *(float4*)&vv[8]  = *(const float4*)(vr + 8);
                *(float4*)&vv[12] = *(const float4*)(vr + 12);
#pragma unroll
                for (int d = 0; d < 16; ++d) Vt[d * 260 + ht] = vv[d];
            }
            if (w == 0) { if (lane < 2) { sred[lane * 2] = sbuf[l * 16 + lane * 0 + hh]; } }
            // (edge scalars precomputed in P0's sbuf)
            __syncthreads();
            float s1  = sbuf[l * 16 + hh];
            float s2g = sbuf[l * 16 + NHEAD + hh];
            int part = lane >> 4, dd = lane & 15;
            for (int it = 0; it < 4; ++it) {
                int r0 = q4 * 64 + w * 16 + it * 4;
                float q[4][16];
#pragma unroll
                for (int rr = 0; rr < 4; ++rr) {
                    const float* qr = big + ((long)(bb * NS + r0 + rr)) * 384 + hh * 16;
                    *(float4*)&q[rr][0]  = *(const float4*)qr;
                    *(float4*)&q[rr][4]  = *(const float4*)(qr + 4);
                    *(float4*)&q[rr][8]  = *(const float4*)(qr + 8);
                    *(float4*)&q[rr][12] = *(const float4*)(qr + 12);
                }
                float sc[4][4];
#pragma unroll
                for (int i = 0; i < 4; ++i) {
                    int c = i * 64 + lane;
                    float kk[16];
                    *(float4*)&kk[0]  = *(const float4*)&Ks[c * 20 + 0];
                    *(float4*)&kk[4]  = *(const float4*)&Ks[c * 20 + 4];
                    *(float4*)&kk[8]  = *(const float4*)&Ks[c * 20 + 8];
                    *(float4*)&kk[12] = *(const float4*)&Ks[c * 20 + 12];
#pragma unroll
                    for (int rr = 0; rr < 4; ++rr) {
                        float d0 = 0.f;
#pragma unroll
                        for (int d = 0; d < 16; ++d) d0 += q[rr][d] * kk[d];
                        sc[rr][i] = d0;
                    }
                }
#pragma unroll
                for (int rr = 0; rr < 4; ++rr) {
                    long eb = ((long)(bb * NS + r0 + rr)) * NS;
                    float e0 = ef[eb + lane],       e1 = ef[eb + 64 + lane];
                    float e2 = ef[eb + 128 + lane], e3 = ef[eb + 192 + lane];
                    float x0 = sc[rr][0] * 0.25f + e0 * s1;
                    float x1 = sc[rr][1] * 0.25f + e1 * s1;
                    float x2 = sc[rr][2] * 0.25f + e2 * s1;
                    float x3 = sc[rr][3] * 0.25f + e3 * s1;
                    float m = fmaxf(fmaxf(x0, x1), fmaxf(x2, x3));
#pragma unroll
                    for (int o = 32; o; o >>= 1) m = fmaxf(m, __shfl_xor(m, o));
                    float p0 = __expf(x0 - m), p1 = __expf(x1 - m);
                    float p2 = __expf(x2 - m), p3 = __expf(x3 - m);
                    float sum = p0 + p1 + p2 + p3;
#pragma unroll
                    for (int o = 32; o; o >>= 1) sum += __shfl_xor(sum, o);
                    float inv = s2g / sum;
                    float* pbr = Pb + (w * 4 + rr) * 256;
                    pbr[lane]       = p0 * inv * e0;
                    pbr[64 + lane]  = p1 * inv * e1;
                    pbr[128 + lane] = p2 * inv * e2;
                    pbr[192 + lane] = p3 * inv * e3;
                }
                __syncthreads();
                float a0 = 0.f, a1 = 0.f, a2 = 0.f, a3 = 0.f;
#pragma unroll
                for (int ii = 0; ii < 16; ++ii) {
                    int c = part * 64 + ((ii + part * 4) & 15) * 4;
                    float4 vv = *(const float4*)&Vt[dd * 260 + c];
                    float4 p;
                    p = *(const float4*)&Pb[(w*4+0)*256 + c]; a0 += vv.x*p.x + vv.y*p.y + vv.z*p.z + vv.w*p.w;
                    p = *(const float4*)&Pb[(w*4+1)*256 + c]; a1 += vv.x*p.x + vv.y*p.y + vv.z*p.z + vv.w*p.w;
                    p = *(const float4*)&Pb[(w*4+2)*256 + c]; a2 += vv.x*p.x + vv.y*p.y + vv.z*p.z + vv.w*p.w;
                    p = *(const float4*)&Pb[(w*4+3)*256 + c]; a3 += vv.x*p.x + vv.y*p.y + vv.z*p.z + vv.w*p.w;
                }
                a0 += __shfl_xor(a0, 16); a0 += __shfl_xor(a0, 32);
                a1 += __shfl_xor(a1, 16); a1 += __shfl_xor(a1, 32);
                a2 += __shfl_xor(a2, 16); a2 += __shfl_xor(a2, 32);
                a3 += __shfl_xor(a3, 16); a3 += __shfl_xor(a3, 32);
                if (lane < 16) {
                    y[((long)(bb * NS + r0 + 0)) * HID + hh * 16 + dd] = a0;
                    y[((long)(bb * NS + r0 + 1)) * HID + hh * 16 + dd] = a1;
                    y[((long)(bb * NS + r0 + 2)) * HID + hh * 16 + dd] = a2;
                    y[((long)(bb * NS + r0 + 3)) * HID + hh * 16 + dd] = a3;
                }
                __syncthreads();
            }
        }
        gsync(cnt, gen);

        // ---- P3: LN2(y+h) + W1 GEMM + relu. 512 tiles (64 x 8).
        {
            float* Ast = (float*)(sm + u * 71680);
            float* Ws  = Ast + 128 * 72;
            int ct = nu >> 6, rt = nu & 63;
            lngemm_tile(y, h, ln2g + l * HID, ln2b + l * HID,
                        W1 + (long)l * HID * 512, big, 512,
                        rt * 64, ct * 64, 1, 1, Ast, Ws, ht);
        }
        gsync(cnt, gen);

        // ---- P4: h = big @ W2 + y. 512 tiles of 32x32, K=512, BK=64.
        {
            float* A2  = (float*)(sm + u * 17920);   // [64][34] transposed
            float* W2s = A2 + 64 * 34;               // [64][36]
            int ct = nu & 3, rt = nu >> 2;
            int row0 = rt * 32, col0 = ct * 32;
            int tx2 = ht & 15, ty2 = ht >> 4;
            float acc[2][2] = {};
            int am = ht >> 3, ak0 = (ht & 7) * 8;
            int wk = ht >> 2, wn = (ht & 3) * 8;
            for (int kc = 0; kc < 512; kc += 64) {
                const float* ap = big + (long)(row0 + am) * 512 + kc + ak0;
                float4 a0 = *(const float4*)ap;
                float4 a1 = *(const float4*)(ap + 4);
                const float* wp = W2 + (long)l * 512 * HID + (long)(kc + wk) * HID + col0 + wn;
                *(float4*)&W2s[wk * 36 + wn]     = *(const float4*)wp;
                *(float4*)&W2s[wk * 36 + wn + 4] = *(const float4*)(wp + 4);
                A2[(ak0+0)*34 + am] = a0.x; A2[(ak0+1)*34 + am] = a0.y;
                A2[(ak0+2)*34 + am] = a0.z; A2[(ak0+3)*34 + am] = a0.w;
                A2[(ak0+4)*34 + am] = a1.x; A2[(ak0+5)*34 + am] = a1.y;
                A2[(ak0+6)*34 + am] = a1.z; A2[(ak0+7)*34 + am] = a1.w;
                __syncthreads();
#pragma unroll
                for (int k = 0; k < 64; ++k) {
                    float2 a2v = *(const float2*)&A2[k * 34 + ty2 * 2];
                    float2 w2v = *(const float2*)&W2s[k * 36 + tx2 * 2];
                    acc[0][0] += a2v.x * w2v.x; acc[0][1] += a2v.x * w2v.y;
                    acc[1][0] += a2v.y * w2v.x; acc[1][1] += a2v.y * w2v.y;
                }
                __syncthreads();
            }
#pragma unroll
            for (int i = 0; i < 2; ++i) {
                int row = row0 + ty2 * 2 + i, col = col0 + tx2 * 2;
                float2 v;
                v.x = acc[i][0] + y[(long)row * HID + col];
                v.y = acc[i][1] + y[(long)row * HID + col + 1];
                *(float2*)&h[(long)row * HID + col] = v;
            }
        }
        gsync(cnt, gen);
    }

    // ---- P5: decode. 16 rows per block, one wave handles 2 rows.
    {
        int w8 = t >> 6, lane = t & 63;
#pragma unroll
        for (int r = 0; r < 2; ++r) {
            int row = blockIdx.x * 16 + w8 * 2 + r;
            float a = h[(long)row * HID + lane] * Wdec[lane]
                    + h[(long)row * HID + 64 + lane] * Wdec[64 + lane];
#pragma unroll
            for (int o = 32; o; o >>= 1) a += __shfl_xor(a, o);
            if (lane == 0) out[row] = 10.f * tanhf(a * 0.08838834764831845f);
        }
    }
}

extern "C" void kernel_launch(void* const* d_in, const int* in_sizes, int n_in,
                              void* d_out, int out_size, void* d_ws, size_t ws_size,
                              hipStream_t stream) {
    const float* nf    = (const float*)d_in[0];
    const float* ef    = (const float*)d_in[1];
    const float* Wn    = (const float*)d_in[2];
    const float* We_in = (const float*)d_in[3];
    const float* ln1g  = (const float*)d_in[4];
    const float* ln1b  = (const float*)d_in[5];
    const float* Wh    = (const float*)d_in[6];
    const float* We    = (const float*)d_in[7];
    const float* ln2g  = (const float*)d_in[8];
    const float* ln2b  = (const float*)d_in[9];
    const float* W1    = (const float*)d_in[10];
    const float* W2    = (const float*)d_in[11];
    const float* Wdec  = (const float*)d_in[12];

    float* ws   = (float*)d_ws;
    int*   bar  = (int*)ws;            // [0..15]
    float* sbuf = ws + 16;             // 48 edge scalars
    float* h    = ws + 64;             // 4096*128
    float* y    = h + ROWS * HID;      // 4096*128
    float* big  = y + ROWS * HID;      // 4096*512 (qkv / mlp hidden)

    static int attr_set = 0;
    if (!attr_set) {
        hipFuncSetAttribute((const void*)k_mega,
                            hipFuncAttributeMaxDynamicSharedMemorySize, 143360);
        attr_set = 1;
    }

    k_init<<<1, 64, 0, stream>>>(bar);
    k_mega<<<NBLK, BT, 143360, stream>>>(nf, ef, Wn, We_in, We, ln1g, ln1b, Wh,
                                         ln2g, ln2b, W1, W2, Wdec,
                                         h, y, big, sbuf, bar, (float*)d_out);
}

// Round 6
// 274.703 us; speedup vs baseline: 3.4477x; 3.4477x over previous
//
#include <hip/hip_runtime.h>
#include <math.h>

#define HID 128
#define NHEAD 8
#define NL 3
#define NS 256
#define ROWS 4096

typedef __attribute__((ext_vector_type(8))) short bf16x8;
typedef __attribute__((ext_vector_type(4))) float f32x4;

__device__ __forceinline__ float us2f(unsigned short s) { return __uint_as_float(((unsigned)s) << 16); }
__device__ __forceinline__ unsigned short f2b(float f) {   // RNE fp32->bf16
    unsigned u = __float_as_uint(f);
    return (unsigned short)((u + 0x7fff + ((u >> 16) & 1)) >> 16);
}

// ---------- prep: split+transpose weights to bf16 hi/lo planes [N][K]; + edge scalars
// blocks: [0,144) Wh tiles, [144,336) W1, [336,528) W2, 528 = edge scalars.
__global__ __launch_bounds__(256) void k_prep(
    const float* __restrict__ Wh, const float* __restrict__ W1, const float* __restrict__ W2,
    const float* __restrict__ We_in, const float* __restrict__ We,
    unsigned short* __restrict__ WhH, unsigned short* __restrict__ WhL,
    unsigned short* __restrict__ W1H, unsigned short* __restrict__ W1L,
    unsigned short* __restrict__ W2H, unsigned short* __restrict__ W2L,
    float* __restrict__ sbuf)
{
    int b = blockIdx.x, t = threadIdx.x;
    if (b == 528) {
        if (t < NL * 2 * NHEAD) {
            int l = t / (2 * NHEAD), j = t % (2 * NHEAD);
            float acc = 0.f;
            for (int c = 0; c < HID; ++c)
                acc += We_in[c] * We[(long)(l * HID + c) * (2 * NHEAD) + j];
            sbuf[t] = acc;
        }
        return;
    }
    const float* S; unsigned short *OH, *OL; int K, N, kt, nt;
    if (b < 144) {
        int l = b / 48, rem = b % 48; kt = rem & 3; nt = rem >> 2; K = 128; N = 384;
        S = Wh + (long)l * 128 * 384; OH = WhH + (long)l * 384 * 128; OL = WhL + (long)l * 384 * 128;
    } else if (b < 336) {
        int b2 = b - 144; int l = b2 / 64, rem = b2 % 64; kt = rem & 3; nt = rem >> 2; K = 128; N = 512;
        S = W1 + (long)l * 128 * 512; OH = W1H + (long)l * 512 * 128; OL = W1L + (long)l * 512 * 128;
    } else {
        int b2 = b - 336; int l = b2 / 64, rem = b2 % 64; kt = rem & 15; nt = rem >> 4; K = 512; N = 128;
        S = W2 + (long)l * 512 * 128; OH = W2H + (long)l * 128 * 512; OL = W2L + (long)l * 128 * 512;
    }
    __shared__ float sm[32][33];
    int i0 = t >> 5, j = t & 31;
#pragma unroll
    for (int p = 0; p < 4; ++p) {
        int i = i0 + p * 8;
        sm[i][j] = S[(long)(kt * 32 + i) * N + nt * 32 + j];
    }
    __syncthreads();
#pragma unroll
    for (int p = 0; p < 4; ++p) {
        int n = i0 + p * 8;
        float v = sm[j][n];                       // = S[kt*32+j][nt*32+n]
        unsigned short hh = f2b(v);
        long o = (long)(nt * 32 + n) * K + kt * 32 + j;
        OH[o] = hh; OL[o] = f2b(v - us2f(hh));
    }
}

// ---------- h0 = nf @ Wn (K=2)
__global__ void k_embed(const float* __restrict__ nf, const float* __restrict__ Wn,
                        float* __restrict__ h) {
    int idx = blockIdx.x * 256 + threadIdx.x;
    int r = idx >> 7, c = idx & 127;
    h[idx] = nf[2 * r] * Wn[c] + nf[2 * r + 1] * Wn[HID + c];
}

// ---------- LayerNorm -> bf16 hi/lo planes. One wave per row.
__global__ __launch_bounds__(256) void k_ln(const float* __restrict__ x,
                                            const float* __restrict__ x2,
                                            const float* __restrict__ g,
                                            const float* __restrict__ b,
                                            unsigned short* __restrict__ oh,
                                            unsigned short* __restrict__ ol) {
    int w = threadIdx.x >> 6, lane = threadIdx.x & 63;
    int row = blockIdx.x * 4 + w;
    int base = row * HID;
    float v0 = x[base + lane], v1 = x[base + 64 + lane];
    if (x2) { v0 += x2[base + lane]; v1 += x2[base + 64 + lane]; }
    float s = v0 + v1, s2 = v0 * v0 + v1 * v1;
#pragma unroll
    for (int o = 32; o; o >>= 1) { s += __shfl_xor(s, o); s2 += __shfl_xor(s2, o); }
    float mu  = s * (1.f / HID);
    float var = s2 * (1.f / HID) - mu * mu;
    float inv = rsqrtf(var + 1e-5f);
    float o0 = (v0 - mu) * inv * g[lane]      + b[lane];
    float o1 = (v1 - mu) * inv * g[64 + lane] + b[64 + lane];
    unsigned short h0 = f2b(o0), h1 = f2b(o1);
    oh[base + lane] = h0;       ol[base + lane] = f2b(o0 - us2f(h0));
    oh[base + 64 + lane] = h1;  ol[base + 64 + lane] = f2b(o1 - us2f(h1));
}

// ---------- split-bf16 MFMA GEMM: 64x64 tile/block, 4 waves (16 rows each), K-slabs of 64.
// A planes [M][K], W planes transposed [N][K]. 3 mfma per term (hh, hl, lh) ~ fp32 accuracy.
// mode 0: Cf = acc    mode 1: relu -> Ch/Cl planes    mode 2: Cf = acc + res
__global__ __launch_bounds__(256, 4) void k_gemm(
    const unsigned short* __restrict__ Ah, const unsigned short* __restrict__ Al,
    const unsigned short* __restrict__ WH, const unsigned short* __restrict__ WL,
    float* __restrict__ Cf, unsigned short* __restrict__ Ch, unsigned short* __restrict__ Cl,
    const float* __restrict__ res, int Nc, int K, int mode)
{
    __shared__ unsigned short sAh[64 * 72], sAl[64 * 72], sWh[64 * 72], sWl[64 * 72]; // 36 KB
    int t = threadIdx.x;
    int row0 = blockIdx.y * 64, col0 = blockIdx.x * 64;
    int w = t >> 6, lane = t & 63;
    int m = lane & 15, quad = lane >> 4;
    f32x4 acc[4];
#pragma unroll
    for (int i = 0; i < 4; ++i) acc[i] = (f32x4){0.f, 0.f, 0.f, 0.f};

    for (int ks = 0; ks < K; ks += 64) {
        if (ks) __syncthreads();
        int r = t >> 3, ck = t & 7;
#pragma unroll
        for (int p = 0; p < 2; ++p) {
            int rr = r + p * 32;
            long ga = (long)(row0 + rr) * K + ks + ck * 8;
            long wa = (long)(col0 + rr) * K + ks + ck * 8;
            *(uint4*)&sAh[rr * 72 + ck * 8] = *(const uint4*)&Ah[ga];
            *(uint4*)&sAl[rr * 72 + ck * 8] = *(const uint4*)&Al[ga];
            *(uint4*)&sWh[rr * 72 + ck * 8] = *(const uint4*)&WH[wa];
            *(uint4*)&sWl[rr * 72 + ck * 8] = *(const uint4*)&WL[wa];
        }
        __syncthreads();
#pragma unroll
        for (int c = 0; c < 2; ++c) {
            bf16x8 ah = *(const bf16x8*)&sAh[(w * 16 + m) * 72 + c * 32 + quad * 8];
            bf16x8 al = *(const bf16x8*)&sAl[(w * 16 + m) * 72 + c * 32 + quad * 8];
#pragma unroll
            for (int nt = 0; nt < 4; ++nt) {
                bf16x8 wh = *(const bf16x8*)&sWh[(nt * 16 + m) * 72 + c * 32 + quad * 8];
                bf16x8 wl = *(const bf16x8*)&sWl[(nt * 16 + m) * 72 + c * 32 + quad * 8];
                acc[nt] = __builtin_amdgcn_mfma_f32_16x16x32_bf16(ah, wh, acc[nt], 0, 0, 0);
                acc[nt] = __builtin_amdgcn_mfma_f32_16x16x32_bf16(ah, wl, acc[nt], 0, 0, 0);
                acc[nt] = __builtin_amdgcn_mfma_f32_16x16x32_bf16(al, wh, acc[nt], 0, 0, 0);
            }
        }
    }
    // epilogue: C/D layout col=lane&15, row=quad*4+reg (within this wave's 16-row strip)
#pragma unroll
    for (int nt = 0; nt < 4; ++nt) {
#pragma unroll
        for (int r = 0; r < 4; ++r) {
            int row = row0 + w * 16 + quad * 4 + r;
            int col = col0 + nt * 16 + m;
            float v = acc[nt][r];
            if (mode == 0) {
                Cf[(long)row * Nc + col] = v;
            } else if (mode == 1) {
                v = fmaxf(v, 0.f);
                unsigned short hh = f2b(v);
                Ch[(long)row * Nc + col] = hh;
                Cl[(long)row * Nc + col] = f2b(v - us2f(hh));
            } else {
                Cf[(long)row * Nc + col] = v + res[(long)row * Nc + col];
            }
        }
    }
}

// ---------- attention (round-3 proven fp32 path): grid 512 = b x head x quarter
__global__ __launch_bounds__(256) void k_attn(const float* __restrict__ qkv,
                                              const float* __restrict__ ef,
                                              const float* __restrict__ sbuf,
                                              int layer,
                                              float* __restrict__ y) {
    __shared__ float Ks[NS][20];
    __shared__ float Vt[16][NS + 4];
    __shared__ float Pb[4][4][NS];
    int bid = blockIdx.x;
    int q4 = bid & 3, hh = (bid >> 2) & 7, bb = bid >> 5;
    int t = threadIdx.x;
    {
        const float* kr = qkv + ((long)(bb * NS + t)) * 384 + HID + hh * 16;
        *(float4*)&Ks[t][0]  = *(const float4*)kr;
        *(float4*)&Ks[t][4]  = *(const float4*)(kr + 4);
        *(float4*)&Ks[t][8]  = *(const float4*)(kr + 8);
        *(float4*)&Ks[t][12] = *(const float4*)(kr + 12);
        const float* vr = kr + HID;
        float vv[16];
        *(float4*)&vv[0]  = *(const float4*)vr;
        *(float4*)&vv[4]  = *(const float4*)(vr + 4);
        *(float4*)&vv[8]  = *(const float4*)(vr + 8);
        *(float4*)&vv[12] = *(const float4*)(vr + 12);
#pragma unroll
        for (int d = 0; d < 16; ++d) Vt[d][t] = vv[d];
    }
    __syncthreads();
    int w = t >> 6, lane = t & 63;
    float s1  = sbuf[layer * 16 + hh];
    float s2g = sbuf[layer * 16 + NHEAD + hh];
    int part = lane >> 4, dd = lane & 15;
    for (int it = 0; it < 4; ++it) {
        int r0 = q4 * 64 + w * 16 + it * 4;
        float q[4][16];
#pragma unroll
        for (int rr = 0; rr < 4; ++rr) {
            const float* qr = qkv + ((long)(bb * NS + r0 + rr)) * 384 + hh * 16;
            *(float4*)&q[rr][0]  = *(const float4*)qr;
            *(float4*)&q[rr][4]  = *(const float4*)(qr + 4);
            *(float4*)&q[rr][8]  = *(const float4*)(qr + 8);
            *(float4*)&q[rr][12] = *(const float4*)(qr + 12);
        }
        float sc[4][4];
#pragma unroll
        for (int i = 0; i < 4; ++i) {
            int c = i * 64 + lane;
            float kk[16];
            *(float4*)&kk[0]  = *(const float4*)&Ks[c][0];
            *(float4*)&kk[4]  = *(const float4*)&Ks[c][4];
            *(float4*)&kk[8]  = *(const float4*)&Ks[c][8];
            *(float4*)&kk[12] = *(const float4*)&Ks[c][12];
#pragma unroll
            for (int rr = 0; rr < 4; ++rr) {
                float d0 = 0.f;
#pragma unroll
                for (int d = 0; d < 16; ++d) d0 += q[rr][d] * kk[d];
                sc[rr][i] = d0;
            }
        }
#pragma unroll
        for (int rr = 0; rr < 4; ++rr) {
            long eb = ((long)(bb * NS + r0 + rr)) * NS;
            float e0 = ef[eb + lane],       e1 = ef[eb + 64 + lane];
            float e2 = ef[eb + 128 + lane], e3 = ef[eb + 192 + lane];
            float x0 = sc[rr][0] * 0.25f + e0 * s1;
            float x1 = sc[rr][1] * 0.25f + e1 * s1;
            float x2 = sc[rr][2] * 0.25f + e2 * s1;
            float x3 = sc[rr][3] * 0.25f + e3 * s1;
            float m = fmaxf(fmaxf(x0, x1), fmaxf(x2, x3));
#pragma unroll
            for (int o = 32; o; o >>= 1) m = fmaxf(m, __shfl_xor(m, o));
            float p0 = __expf(x0 - m), p1 = __expf(x1 - m);
            float p2 = __expf(x2 - m), p3 = __expf(x3 - m);
            float sum = p0 + p1 + p2 + p3;
#pragma unroll
            for (int o = 32; o; o >>= 1) sum += __shfl_xor(sum, o);
            float inv = s2g / sum;
            Pb[w][rr][lane]       = p0 * inv * e0;
            Pb[w][rr][64 + lane]  = p1 * inv * e1;
            Pb[w][rr][128 + lane] = p2 * inv * e2;
            Pb[w][rr][192 + lane] = p3 * inv * e3;
        }
        __syncthreads();
        float a0 = 0.f, a1 = 0.f, a2 = 0.f, a3 = 0.f;
#pragma unroll
        for (int ii = 0; ii < 16; ++ii) {
            int c = part * 64 + ((ii + part * 4) & 15) * 4;
            float4 vv = *(const float4*)&Vt[dd][c];
            float4 p;
            p = *(const float4*)&Pb[w][0][c]; a0 += vv.x*p.x + vv.y*p.y + vv.z*p.z + vv.w*p.w;
            p = *(const float4*)&Pb[w][1][c]; a1 += vv.x*p.x + vv.y*p.y + vv.z*p.z + vv.w*p.w;
            p = *(const float4*)&Pb[w][2][c]; a2 += vv.x*p.x + vv.y*p.y + vv.z*p.z + vv.w*p.w;
            p = *(const float4*)&Pb[w][3][c]; a3 += vv.x*p.x + vv.y*p.y + vv.z*p.z + vv.w*p.w;
        }
        a0 += __shfl_xor(a0, 16); a0 += __shfl_xor(a0, 32);
        a1 += __shfl_xor(a1, 16); a1 += __shfl_xor(a1, 32);
        a2 += __shfl_xor(a2, 16); a2 += __shfl_xor(a2, 32);
        a3 += __shfl_xor(a3, 16); a3 += __shfl_xor(a3, 32);
        if (lane < 16) {
            y[((long)(bb * NS + r0 + 0)) * HID + hh * 16 + dd] = a0;
            y[((long)(bb * NS + r0 + 1)) * HID + hh * 16 + dd] = a1;
            y[((long)(bb * NS + r0 + 2)) * HID + hh * 16 + dd] = a2;
            y[((long)(bb * NS + r0 + 3)) * HID + hh * 16 + dd] = a3;
        }
        __syncthreads();
    }
}

// ---------- out = 10*tanh((h @ Wdec)/sqrt(128))
__global__ __launch_bounds__(256) void k_dec(const float* __restrict__ h,
                                             const float* __restrict__ Wdec,
                                             float* __restrict__ out) {
    int w = threadIdx.x >> 6, lane = threadIdx.x & 63;
    int row = blockIdx.x * 4 + w;
    float a = h[(long)row * HID + lane] * Wdec[lane]
            + h[(long)row * HID + 64 + lane] * Wdec[64 + lane];
#pragma unroll
    for (int o = 32; o; o >>= 1) a += __shfl_xor(a, o);
    if (lane == 0) out[row] = 10.f * tanhf(a * 0.08838834764831845f);
}

extern "C" void kernel_launch(void* const* d_in, const int* in_sizes, int n_in,
                              void* d_out, int out_size, void* d_ws, size_t ws_size,
                              hipStream_t stream) {
    const float* nf    = (const float*)d_in[0];
    const float* ef    = (const float*)d_in[1];
    const float* Wn    = (const float*)d_in[2];
    const float* We_in = (const float*)d_in[3];
    const float* ln1g  = (const float*)d_in[4];
    const float* ln1b  = (const float*)d_in[5];
    const float* Wh    = (const float*)d_in[6];
    const float* We    = (const float*)d_in[7];
    const float* ln2g  = (const float*)d_in[8];
    const float* ln2b  = (const float*)d_in[9];
    const float* W1    = (const float*)d_in[10];
    const float* W2    = (const float*)d_in[11];
    const float* Wdec  = (const float*)d_in[12];

    float* ws   = (float*)d_ws;
    float* sbuf = ws;                            // 64 slots
    float* h    = ws + 64;                       // 4096*128
    float* y    = h + ROWS * HID;                // 4096*128
    float* qkv  = y + ROWS * HID;                // 4096*384
    unsigned short* hnH  = (unsigned short*)(qkv + (long)ROWS * 384);
    unsigned short* hnL  = hnH + (long)ROWS * HID;
    unsigned short* hidH = hnL + (long)ROWS * HID;          // 4096*512
    unsigned short* hidL = hidH + (long)ROWS * 512;
    unsigned short* WhH  = hidL + (long)ROWS * 512;          // 3*384*128
    unsigned short* WhL  = WhH + (long)NL * 384 * 128;
    unsigned short* W1H  = WhL + (long)NL * 384 * 128;       // 3*512*128
    unsigned short* W1L  = W1H + (long)NL * 512 * 128;
    unsigned short* W2H  = W1L + (long)NL * 512 * 128;       // 3*128*512
    unsigned short* W2L  = W2H + (long)NL * 128 * 512;

    k_prep<<<529, 256, 0, stream>>>(Wh, W1, W2, We_in, We,
                                    WhH, WhL, W1H, W1L, W2H, W2L, sbuf);
    k_embed<<<ROWS * HID / 256, 256, 0, stream>>>(nf, Wn, h);
    for (int l = 0; l < NL; ++l) {
        k_ln<<<ROWS / 4, 256, 0, stream>>>(h, nullptr, ln1g + l * HID, ln1b + l * HID, hnH, hnL);
        k_gemm<<<dim3(6, 64), 256, 0, stream>>>(hnH, hnL,
            WhH + (long)l * 384 * 128, WhL + (long)l * 384 * 128,
            qkv, nullptr, nullptr, nullptr, 384, 128, 0);
        k_attn<<<512, 256, 0, stream>>>(qkv, ef, sbuf, l, y);
        k_ln<<<ROWS / 4, 256, 0, stream>>>(y, h, ln2g + l * HID, ln2b + l * HID, hnH, hnL);
        k_gemm<<<dim3(8, 64), 256, 0, stream>>>(hnH, hnL,
            W1H + (long)l * 512 * 128, W1L + (long)l * 512 * 128,
            nullptr, hidH, hidL, nullptr, 512, 128, 1);
        k_gemm<<<dim3(2, 64), 256, 0, stream>>>(hidH, hidL,
            W2H + (long)l * 128 * 512, W2L + (long)l * 128 * 512,
            h, nullptr, nullptr, y, 128, 512, 2);
    }
    k_dec<<<ROWS / 4, 256, 0, stream>>>(h, Wdec, (float*)d_out);
}

// Round 7
// 243.817 us; speedup vs baseline: 3.8845x; 1.1267x over previous
//
#include <hip/hip_runtime.h>
#include <math.h>

#define HID 128
#define NHEAD 8
#define NL 3
#define NS 256
#define ROWS 4096

typedef __attribute__((ext_vector_type(8))) short bf16x8;
typedef __attribute__((ext_vector_type(4))) float f32x4;

__device__ __forceinline__ float us2f(unsigned short s) { return __uint_as_float(((unsigned)s) << 16); }
__device__ __forceinline__ unsigned short f2b(float f) {   // RNE fp32->bf16
    unsigned u = __float_as_uint(f);
    return (unsigned short)((u + 0x7fff + ((u >> 16) & 1)) >> 16);
}

// ---------- prep: split+transpose weights to bf16 hi/lo planes [N][K]; + edge scalars
// blocks: [0,144) Wh tiles, [144,336) W1, [336,528) W2, 528 = edge scalars.
__global__ __launch_bounds__(256) void k_prep(
    const float* __restrict__ Wh, const float* __restrict__ W1, const float* __restrict__ W2,
    const float* __restrict__ We_in, const float* __restrict__ We,
    unsigned short* __restrict__ WhH, unsigned short* __restrict__ WhL,
    unsigned short* __restrict__ W1H, unsigned short* __restrict__ W1L,
    unsigned short* __restrict__ W2H, unsigned short* __restrict__ W2L,
    float* __restrict__ sbuf)
{
    int b = blockIdx.x, t = threadIdx.x;
    if (b == 528) {
        if (t < NL * 2 * NHEAD) {
            int l = t / (2 * NHEAD), j = t % (2 * NHEAD);
            float acc = 0.f;
            for (int c = 0; c < HID; ++c)
                acc += We_in[c] * We[(long)(l * HID + c) * (2 * NHEAD) + j];
            sbuf[t] = acc;
        }
        return;
    }
    const float* S; unsigned short *OH, *OL; int K, N, kt, nt;
    if (b < 144) {
        int l = b / 48, rem = b % 48; kt = rem & 3; nt = rem >> 2; K = 128; N = 384;
        S = Wh + (long)l * 128 * 384; OH = WhH + (long)l * 384 * 128; OL = WhL + (long)l * 384 * 128;
    } else if (b < 336) {
        int b2 = b - 144; int l = b2 / 64, rem = b2 % 64; kt = rem & 3; nt = rem >> 2; K = 128; N = 512;
        S = W1 + (long)l * 128 * 512; OH = W1H + (long)l * 512 * 128; OL = W1L + (long)l * 512 * 128;
    } else {
        int b2 = b - 336; int l = b2 / 64, rem = b2 % 64; kt = rem & 15; nt = rem >> 4; K = 512; N = 128;
        S = W2 + (long)l * 512 * 128; OH = W2H + (long)l * 128 * 512; OL = W2L + (long)l * 128 * 512;
    }
    __shared__ float sm[32][33];
    int i0 = t >> 5, j = t & 31;
#pragma unroll
    for (int p = 0; p < 4; ++p) {
        int i = i0 + p * 8;
        sm[i][j] = S[(long)(kt * 32 + i) * N + nt * 32 + j];
    }
    __syncthreads();
#pragma unroll
    for (int p = 0; p < 4; ++p) {
        int n = i0 + p * 8;
        float v = sm[j][n];                       // = S[kt*32+j][nt*32+n]
        unsigned short hh = f2b(v);
        long o = (long)(nt * 32 + n) * K + kt * 32 + j;
        OH[o] = hh; OL[o] = f2b(v - us2f(hh));
    }
}

// ---------- embed + LN1(layer0): h = nf@Wn, planes = LN(h). One wave per row.
__global__ __launch_bounds__(256) void k_embln(
    const float* __restrict__ nf, const float* __restrict__ Wn,
    const float* __restrict__ g, const float* __restrict__ b,
    float* __restrict__ h, unsigned short* __restrict__ oh, unsigned short* __restrict__ ol)
{
    int w = threadIdx.x >> 6, lane = threadIdx.x & 63;
    int row = blockIdx.x * 4 + w;
    int base = row * HID;
    float n0 = nf[2 * row], n1 = nf[2 * row + 1];
    float v0 = n0 * Wn[lane]      + n1 * Wn[HID + lane];
    float v1 = n0 * Wn[64 + lane] + n1 * Wn[HID + 64 + lane];
    h[base + lane] = v0; h[base + 64 + lane] = v1;
    float s = v0 + v1, s2 = v0 * v0 + v1 * v1;
#pragma unroll
    for (int o = 32; o; o >>= 1) { s += __shfl_xor(s, o); s2 += __shfl_xor(s2, o); }
    float mu  = s * (1.f / HID);
    float var = s2 * (1.f / HID) - mu * mu;
    float inv = rsqrtf(var + 1e-5f);
    float o0 = (v0 - mu) * inv * g[lane]      + b[lane];
    float o1 = (v1 - mu) * inv * g[64 + lane] + b[64 + lane];
    unsigned short h0 = f2b(o0), h1 = f2b(o1);
    oh[base + lane] = h0;       ol[base + lane] = f2b(o0 - us2f(h0));
    oh[base + 64 + lane] = h1;  ol[base + 64 + lane] = f2b(o1 - us2f(h1));
}

// ---------- LayerNorm (LN2) -> bf16 hi/lo planes. One wave per row.
__global__ __launch_bounds__(256) void k_ln(const float* __restrict__ x,
                                            const float* __restrict__ x2,
                                            const float* __restrict__ g,
                                            const float* __restrict__ b,
                                            unsigned short* __restrict__ oh,
                                            unsigned short* __restrict__ ol) {
    int w = threadIdx.x >> 6, lane = threadIdx.x & 63;
    int row = blockIdx.x * 4 + w;
    int base = row * HID;
    float v0 = x[base + lane] + x2[base + lane];
    float v1 = x[base + 64 + lane] + x2[base + 64 + lane];
    float s = v0 + v1, s2 = v0 * v0 + v1 * v1;
#pragma unroll
    for (int o = 32; o; o >>= 1) { s += __shfl_xor(s, o); s2 += __shfl_xor(s2, o); }
    float mu  = s * (1.f / HID);
    float var = s2 * (1.f / HID) - mu * mu;
    float inv = rsqrtf(var + 1e-5f);
    float o0 = (v0 - mu) * inv * g[lane]      + b[lane];
    float o1 = (v1 - mu) * inv * g[64 + lane] + b[64 + lane];
    unsigned short h0 = f2b(o0), h1 = f2b(o1);
    oh[base + lane] = h0;       ol[base + lane] = f2b(o0 - us2f(h0));
    oh[base + 64 + lane] = h1;  ol[base + 64 + lane] = f2b(o1 - us2f(h1));
}

// ---------- split-bf16 MFMA GEMM: 64x64 tile, 4 waves, K-slabs of 64. K=128 here.
// mode 0: Cf = acc      mode 1: relu -> Ch/Cl planes
__global__ __launch_bounds__(256, 4) void k_gemm(
    const unsigned short* __restrict__ Ah, const unsigned short* __restrict__ Al,
    const unsigned short* __restrict__ WH, const unsigned short* __restrict__ WL,
    float* __restrict__ Cf, unsigned short* __restrict__ Ch, unsigned short* __restrict__ Cl,
    int Nc, int K, int mode)
{
    __shared__ unsigned short sAh[64 * 72], sAl[64 * 72], sWh[64 * 72], sWl[64 * 72]; // 36 KB
    int t = threadIdx.x;
    int row0 = blockIdx.y * 64, col0 = blockIdx.x * 64;
    int w = t >> 6, lane = t & 63;
    int m = lane & 15, quad = lane >> 4;
    f32x4 acc[4];
#pragma unroll
    for (int i = 0; i < 4; ++i) acc[i] = (f32x4){0.f, 0.f, 0.f, 0.f};

    for (int ks = 0; ks < K; ks += 64) {
        if (ks) __syncthreads();
        int r = t >> 3, ck = t & 7;
#pragma unroll
        for (int p = 0; p < 2; ++p) {
            int rr = r + p * 32;
            long ga = (long)(row0 + rr) * K + ks + ck * 8;
            long wa = (long)(col0 + rr) * K + ks + ck * 8;
            *(uint4*)&sAh[rr * 72 + ck * 8] = *(const uint4*)&Ah[ga];
            *(uint4*)&sAl[rr * 72 + ck * 8] = *(const uint4*)&Al[ga];
            *(uint4*)&sWh[rr * 72 + ck * 8] = *(const uint4*)&WH[wa];
            *(uint4*)&sWl[rr * 72 + ck * 8] = *(const uint4*)&WL[wa];
        }
        __syncthreads();
#pragma unroll
        for (int c = 0; c < 2; ++c) {
            bf16x8 ah = *(const bf16x8*)&sAh[(w * 16 + m) * 72 + c * 32 + quad * 8];
            bf16x8 al = *(const bf16x8*)&sAl[(w * 16 + m) * 72 + c * 32 + quad * 8];
#pragma unroll
            for (int nt = 0; nt < 4; ++nt) {
                bf16x8 wh = *(const bf16x8*)&sWh[(nt * 16 + m) * 72 + c * 32 + quad * 8];
                bf16x8 wl = *(const bf16x8*)&sWl[(nt * 16 + m) * 72 + c * 32 + quad * 8];
                acc[nt] = __builtin_amdgcn_mfma_f32_16x16x32_bf16(ah, wh, acc[nt], 0, 0, 0);
                acc[nt] = __builtin_amdgcn_mfma_f32_16x16x32_bf16(ah, wl, acc[nt], 0, 0, 0);
                acc[nt] = __builtin_amdgcn_mfma_f32_16x16x32_bf16(al, wh, acc[nt], 0, 0, 0);
            }
        }
    }
#pragma unroll
    for (int nt = 0; nt < 4; ++nt) {
#pragma unroll
        for (int r = 0; r < 4; ++r) {
            int row = row0 + w * 16 + quad * 4 + r;
            int col = col0 + nt * 16 + m;
            float v = acc[nt][r];
            if (mode == 0) {
                Cf[(long)row * Nc + col] = v;
            } else {
                v = fmaxf(v, 0.f);
                unsigned short hh = f2b(v);
                Ch[(long)row * Nc + col] = hh;
                Cl[(long)row * Nc + col] = f2b(v - us2f(hh));
            }
        }
    }
}

// ---------- W2 GEMM + residual + fused next-layer LN1: 16 rows x 128 cols per block.
// h = hid @ W2 + y ; if g: emit LN1 planes for next layer. Grid 256 blocks.
__global__ __launch_bounds__(256, 3) void k_w2ln(
    const unsigned short* __restrict__ Ah, const unsigned short* __restrict__ Al,   // [4096][512]
    const unsigned short* __restrict__ WH, const unsigned short* __restrict__ WL,   // [128][512]
    const float* __restrict__ yres, float* __restrict__ hout,
    const float* __restrict__ g, const float* __restrict__ b,
    unsigned short* __restrict__ oh, unsigned short* __restrict__ ol)
{
    __shared__ unsigned short sA[2][16 * 72];    // 4.6 KB
    __shared__ unsigned short sW[2][128 * 72];   // 36.9 KB
    int t = threadIdx.x;
    int row0 = blockIdx.x * 16;
    int w = t >> 6, lane = t & 63;
    int m = lane & 15, quad = lane >> 4;
    f32x4 acc[2];
    acc[0] = (f32x4){0.f,0.f,0.f,0.f}; acc[1] = (f32x4){0.f,0.f,0.f,0.f};

    for (int ks = 0; ks < 512; ks += 64) {
        if (ks) __syncthreads();
        {   // A planes: 128 16B-chunks per plane; threads 0-127 hi, 128-255 lo
            int pl = t >> 7, tt = t & 127;
            int r = tt >> 3, ck = tt & 7;
            const unsigned short* src = pl ? Al : Ah;
            *(uint4*)&sA[pl][r * 72 + ck * 8] = *(const uint4*)&src[(long)(row0 + r) * 512 + ks + ck * 8];
        }
        {   // W planes: 128 N-rows x 64k
            int r0 = t >> 3, ck = t & 7;
#pragma unroll
            for (int p = 0; p < 4; ++p) {
                int n = r0 + p * 32;
                *(uint4*)&sW[0][n * 72 + ck * 8] = *(const uint4*)&WH[(long)n * 512 + ks + ck * 8];
                *(uint4*)&sW[1][n * 72 + ck * 8] = *(const uint4*)&WL[(long)n * 512 + ks + ck * 8];
            }
        }
        __syncthreads();
#pragma unroll
        for (int c = 0; c < 2; ++c) {
            bf16x8 ah = *(const bf16x8*)&sA[0][m * 72 + c * 32 + quad * 8];
            bf16x8 al = *(const bf16x8*)&sA[1][m * 72 + c * 32 + quad * 8];
#pragma unroll
            for (int nt = 0; nt < 2; ++nt) {
                int n = w * 32 + nt * 16 + m;
                bf16x8 wh = *(const bf16x8*)&sW[0][n * 72 + c * 32 + quad * 8];
                bf16x8 wl = *(const bf16x8*)&sW[1][n * 72 + c * 32 + quad * 8];
                acc[nt] = __builtin_amdgcn_mfma_f32_16x16x32_bf16(ah, wh, acc[nt], 0, 0, 0);
                acc[nt] = __builtin_amdgcn_mfma_f32_16x16x32_bf16(ah, wl, acc[nt], 0, 0, 0);
                acc[nt] = __builtin_amdgcn_mfma_f32_16x16x32_bf16(al, wh, acc[nt], 0, 0, 0);
            }
        }
    }
    __syncthreads();                    // all sW reads done; reuse as fp32 tile
    float* ht = (float*)&sW[0][0];      // [16][132]
#pragma unroll
    for (int nt = 0; nt < 2; ++nt) {
#pragma unroll
        for (int r = 0; r < 4; ++r) {
            int row = quad * 4 + r;
            int col = w * 32 + nt * 16 + m;
            float v = acc[nt][r] + yres[(long)(row0 + row) * HID + col];
            hout[(long)(row0 + row) * HID + col] = v;
            ht[row * 132 + col] = v;
        }
    }
    __syncthreads();
    if (g) {
        int row = t >> 4, sub = t & 15;       // 16 threads per row, 8 cols each
        float v[8];
        *(float4*)&v[0] = *(const float4*)&ht[row * 132 + sub * 8];
        *(float4*)&v[4] = *(const float4*)&ht[row * 132 + sub * 8 + 4];
        float s = 0.f, s2 = 0.f;
#pragma unroll
        for (int j = 0; j < 8; ++j) { s += v[j]; s2 += v[j] * v[j]; }
        s  += __shfl_xor(s, 1);  s  += __shfl_xor(s, 2);  s  += __shfl_xor(s, 4);  s  += __shfl_xor(s, 8);
        s2 += __shfl_xor(s2, 1); s2 += __shfl_xor(s2, 2); s2 += __shfl_xor(s2, 4); s2 += __shfl_xor(s2, 8);
        float mu  = s * (1.f / HID);
        float var = s2 * (1.f / HID) - mu * mu;
        float inv = rsqrtf(var + 1e-5f);
        long base = (long)(row0 + row) * HID + sub * 8;
#pragma unroll
        for (int j = 0; j < 8; ++j) {
            int c = sub * 8 + j;
            float o = (v[j] - mu) * inv * g[c] + b[c];
            unsigned short hh = f2b(o);
            oh[base + j] = hh; ol[base + j] = f2b(o - us2f(hh));
        }
    }
}

// ---------- attention: grid 512 = b x head x quarter. Pb is per-wave -> no inner barriers.
__global__ __launch_bounds__(256) void k_attn(const float* __restrict__ qkv,
                                              const float* __restrict__ ef,
                                              const float* __restrict__ sbuf,
                                              int layer,
                                              float* __restrict__ y) {
    __shared__ float Ks[NS][20];
    __shared__ float Vt[16][NS + 4];
    __shared__ float Pb[4][4][NS];
    int bid = blockIdx.x;
    int q4 = bid & 3, hh = (bid >> 2) & 7, bb = bid >> 5;
    int t = threadIdx.x;
    {
        const float* kr = qkv + ((long)(bb * NS + t)) * 384 + HID + hh * 16;
        *(float4*)&Ks[t][0]  = *(const float4*)kr;
        *(float4*)&Ks[t][4]  = *(const float4*)(kr + 4);
        *(float4*)&Ks[t][8]  = *(const float4*)(kr + 8);
        *(float4*)&Ks[t][12] = *(const float4*)(kr + 12);
        const float* vr = kr + HID;
        float vv[16];
        *(float4*)&vv[0]  = *(const float4*)vr;
        *(float4*)&vv[4]  = *(const float4*)(vr + 4);
        *(float4*)&vv[8]  = *(const float4*)(vr + 8);
        *(float4*)&vv[12] = *(const float4*)(vr + 12);
#pragma unroll
        for (int d = 0; d < 16; ++d) Vt[d][t] = vv[d];
    }
    __syncthreads();
    int w = t >> 6, lane = t & 63;
    float s1  = sbuf[layer * 16 + hh];
    float s2g = sbuf[layer * 16 + NHEAD + hh];
    int part = lane >> 4, dd = lane & 15;
    for (int it = 0; it < 4; ++it) {
        int r0 = q4 * 64 + w * 16 + it * 4;
        float q[4][16];
#pragma unroll
        for (int rr = 0; rr < 4; ++rr) {
            const float* qr = qkv + ((long)(bb * NS + r0 + rr)) * 384 + hh * 16;
            *(float4*)&q[rr][0]  = *(const float4*)qr;
            *(float4*)&q[rr][4]  = *(const float4*)(qr + 4);
            *(float4*)&q[rr][8]  = *(const float4*)(qr + 8);
            *(float4*)&q[rr][12] = *(const float4*)(qr + 12);
        }
        float sc[4][4];
#pragma unroll
        for (int i = 0; i < 4; ++i) {
            int c = i * 64 + lane;
            float kk[16];
            *(float4*)&kk[0]  = *(const float4*)&Ks[c][0];
            *(float4*)&kk[4]  = *(const float4*)&Ks[c][4];
            *(float4*)&kk[8]  = *(const float4*)&Ks[c][8];
            *(float4*)&kk[12] = *(const float4*)&Ks[c][12];
#pragma unroll
            for (int rr = 0; rr < 4; ++rr) {
                float d0 = 0.f;
#pragma unroll
                for (int d = 0; d < 16; ++d) d0 += q[rr][d] * kk[d];
                sc[rr][i] = d0;
            }
        }
#pragma unroll
        for (int rr = 0; rr < 4; ++rr) {
            long eb = ((long)(bb * NS + r0 + rr)) * NS;
            float e0 = ef[eb + lane],       e1 = ef[eb + 64 + lane];
            float e2 = ef[eb + 128 + lane], e3 = ef[eb + 192 + lane];
            float x0 = sc[rr][0] * 0.25f + e0 * s1;
            float x1 = sc[rr][1] * 0.25f + e1 * s1;
            float x2 = sc[rr][2] * 0.25f + e2 * s1;
            float x3 = sc[rr][3] * 0.25f + e3 * s1;
            float m = fmaxf(fmaxf(x0, x1), fmaxf(x2, x3));
#pragma unroll
            for (int o = 32; o; o >>= 1) m = fmaxf(m, __shfl_xor(m, o));
            float p0 = __expf(x0 - m), p1 = __expf(x1 - m);
            float p2 = __expf(x2 - m), p3 = __expf(x3 - m);
            float sum = p0 + p1 + p2 + p3;
#pragma unroll
            for (int o = 32; o; o >>= 1) sum += __shfl_xor(sum, o);
            float inv = s2g / sum;
            Pb[w][rr][lane]       = p0 * inv * e0;
            Pb[w][rr][64 + lane]  = p1 * inv * e1;
            Pb[w][rr][128 + lane] = p2 * inv * e2;
            Pb[w][rr][192 + lane] = p3 * inv * e3;
        }
        float a0 = 0.f, a1 = 0.f, a2 = 0.f, a3 = 0.f;
#pragma unroll
        for (int ii = 0; ii < 16; ++ii) {
            int c = part * 64 + ((ii + part * 4) & 15) * 4;
            float4 vv = *(const float4*)&Vt[dd][c];
            float4 p;
            p = *(const float4*)&Pb[w][0][c]; a0 += vv.x*p.x + vv.y*p.y + vv.z*p.z + vv.w*p.w;
            p = *(const float4*)&Pb[w][1][c]; a1 += vv.x*p.x + vv.y*p.y + vv.z*p.z + vv.w*p.w;
            p = *(const float4*)&Pb[w][2][c]; a2 += vv.x*p.x + vv.y*p.y + vv.z*p.z + vv.w*p.w;
            p = *(const float4*)&Pb[w][3][c]; a3 += vv.x*p.x + vv.y*p.y + vv.z*p.z + vv.w*p.w;
        }
        a0 += __shfl_xor(a0, 16); a0 += __shfl_xor(a0, 32);
        a1 += __shfl_xor(a1, 16); a1 += __shfl_xor(a1, 32);
        a2 += __shfl_xor(a2, 16); a2 += __shfl_xor(a2, 32);
        a3 += __shfl_xor(a3, 16); a3 += __shfl_xor(a3, 32);
        if (lane < 16) {
            y[((long)(bb * NS + r0 + 0)) * HID + hh * 16 + dd] = a0;
            y[((long)(bb * NS + r0 + 1)) * HID + hh * 16 + dd] = a1;
            y[((long)(bb * NS + r0 + 2)) * HID + hh * 16 + dd] = a2;
            y[((long)(bb * NS + r0 + 3)) * HID + hh * 16 + dd] = a3;
        }
    }
}

// ---------- out = 10*tanh((h @ Wdec)/sqrt(128))
__global__ __launch_bounds__(256) void k_dec(const float* __restrict__ h,
                                             const float* __restrict__ Wdec,
                                             float* __restrict__ out) {
    int w = threadIdx.x >> 6, lane = threadIdx.x & 63;
    int row = blockIdx.x * 4 + w;
    float a = h[(long)row * HID + lane] * Wdec[lane]
            + h[(long)row * HID + 64 + lane] * Wdec[64 + lane];
#pragma unroll
    for (int o = 32; o; o >>= 1) a += __shfl_xor(a, o);
    if (lane == 0) out[row] = 10.f * tanhf(a * 0.08838834764831845f);
}

extern "C" void kernel_launch(void* const* d_in, const int* in_sizes, int n_in,
                              void* d_out, int out_size, void* d_ws, size_t ws_size,
                              hipStream_t stream) {
    const float* nf    = (const float*)d_in[0];
    const float* ef    = (const float*)d_in[1];
    const float* Wn    = (const float*)d_in[2];
    const float* We_in = (const float*)d_in[3];
    const float* ln1g  = (const float*)d_in[4];
    const float* ln1b  = (const float*)d_in[5];
    const float* Wh    = (const float*)d_in[6];
    const float* We    = (const float*)d_in[7];
    const float* ln2g  = (const float*)d_in[8];
    const float* ln2b  = (const float*)d_in[9];
    const float* W1    = (const float*)d_in[10];
    const float* W2    = (const float*)d_in[11];
    const float* Wdec  = (const float*)d_in[12];

    float* ws   = (float*)d_ws;
    float* sbuf = ws;                            // 64 slots
    float* h    = ws + 64;                       // 4096*128
    float* y    = h + ROWS * HID;                // 4096*128
    float* qkv  = y + ROWS * HID;                // 4096*384
    unsigned short* hnH  = (unsigned short*)(qkv + (long)ROWS * 384);
    unsigned short* hnL  = hnH + (long)ROWS * HID;
    unsigned short* hidH = hnL + (long)ROWS * HID;           // 4096*512
    unsigned short* hidL = hidH + (long)ROWS * 512;
    unsigned short* WhH  = hidL + (long)ROWS * 512;          // 3*384*128
    unsigned short* WhL  = WhH + (long)NL * 384 * 128;
    unsigned short* W1H  = WhL + (long)NL * 384 * 128;       // 3*512*128
    unsigned short* W1L  = W1H + (long)NL * 512 * 128;
    unsigned short* W2H  = W1L + (long)NL * 512 * 128;       // 3*128*512
    unsigned short* W2L  = W2H + (long)NL * 128 * 512;

    k_prep<<<529, 256, 0, stream>>>(Wh, W1, W2, We_in, We,
                                    WhH, WhL, W1H, W1L, W2H, W2L, sbuf);
    k_embln<<<ROWS / 4, 256, 0, stream>>>(nf, Wn, ln1g, ln1b, h, hnH, hnL);
    for (int l = 0; l < NL; ++l) {
        k_gemm<<<dim3(6, 64), 256, 0, stream>>>(hnH, hnL,
            WhH + (long)l * 384 * 128, WhL + (long)l * 384 * 128,
            qkv, nullptr, nullptr, 384, 128, 0);
        k_attn<<<512, 256, 0, stream>>>(qkv, ef, sbuf, l, y);
        k_ln<<<ROWS / 4, 256, 0, stream>>>(y, h, ln2g + l * HID, ln2b + l * HID, hnH, hnL);
        k_gemm<<<dim3(8, 64), 256, 0, stream>>>(hnH, hnL,
            W1H + (long)l * 512 * 128, W1L + (long)l * 512 * 128,
            nullptr, hidH, hidL, 512, 128, 1);
        int last = (l == NL - 1);
        k_w2ln<<<ROWS / 16, 256, 0, stream>>>(hidH, hidL,
            W2H + (long)l * 128 * 512, W2L + (long)l * 128 * 512,
            y, h,
            last ? nullptr : ln1g + (l + 1) * HID, last ? nullptr : ln1b + (l + 1) * HID,
            hnH, hnL);
    }
    k_dec<<<ROWS / 4, 256, 0, stream>>>(h, Wdec, (float*)d_out);
}